// Round 6
// baseline (507.560 us; speedup 1.0000x reference)
//
#include <hip/hip_runtime.h>
#include <hip/hip_bf16.h>

// Problem constants (from reference): L layers, B batch, D width.
constexpr int L = 8;
constexpr int B = 32;
constexpr int D = 1280;

constexpr int JT = 64;              // output columns per block (256B/wave-instr, contiguous)
constexpr int ISPLIT = 4;           // i-reduction split across the block's 4 waves
constexpr int BLOCK = JT * ISPLIT;  // 256 threads
constexpr int ICHUNK = D / ISPLIT;  // 320
constexpr int NBB = D / JT;         // 20 blocks per batch
constexpr int PF = 32;              // next-layer W prefetch depth (regs/thread)

// Persistent kernel, grid = (20,32) = 640 blocks (all co-resident: R4 measured
// 28.8% occupancy at this geometry). Inter-layer sync is PER-BATCH among 20
// blocks, handshaking entirely at the LLC (Infinity Cache = the agent
// coherence point): relaxed sc-flagged atomic stores/loads only — NO
// acquire/release cache maintenance (R4's acquire-per-poll L2-invalidate
// storm cost 4.6x). Deadlock-safe without cooperative launch: each batch's
// 20 blocks are consecutive in dispatch order and wait only on each other.
__global__ __launch_bounds__(BLOCK) void fused_kernel(
    const float* __restrict__ x,     // [B, D]
    const float* __restrict__ Wall,  // [L, B, D, D]
    const float* __restrict__ ball,  // [L, B, D]
    const int*   __restrict__ mall,  // [L, B, D]
    float*       __restrict__ out,   // [B, D]
    float*       __restrict__ ws0,   // [B, D] h ping (LLC-resident exchange)
    float*       __restrict__ ws1,   // [B, D] h pong
    int*         __restrict__ cnt)   // [L, B] barrier counters (zeroed per call)
{
    const int b  = blockIdx.y;
    const int j0 = blockIdx.x * JT;
    const int t  = threadIdx.x;
    const int jj = t & (JT - 1);   // 0..63 (lane)
    const int iq = t >> 6;         // 0..3  (wave)
    const int j  = j0 + jj;
    const int i_beg = iq * ICHUNK;

    __shared__ float hs[D];
    __shared__ float partial[BLOCK];

    // Prefetch first PF W rows of layer 0 while staging h0.
    const float* w = Wall + (size_t)b * D * D + j;
    float pf[PF];
#pragma unroll
    for (int k = 0; k < PF; ++k) pf[k] = w[(size_t)(i_beg + k) * D];

    // Layer-0 h staging from x (normal cached loads).
    {
        const float4* src = (const float4*)(x + b * D);
        float4* dst = (float4*)hs;
        for (int k = t; k < D / 4; k += BLOCK) dst[k] = src[k];
    }
    __syncthreads();

    for (int l = 0; l < L; ++l) {
        // i-reduction: first PF iters consume prefetched regs, rest stream W.
        float acc = 0.f;
#pragma unroll
        for (int k = 0; k < PF; ++k) acc = fmaf(hs[i_beg + k], pf[k], acc);
#pragma unroll 16
        for (int i = i_beg + PF; i < i_beg + ICHUNK; ++i)
            acc = fmaf(hs[i], w[(size_t)i * D], acc);

        partial[t] = acc;
        __syncthreads();   // partials ready; also: everyone done reading hs

        const bool last = (l == L - 1);
        float* hout = last ? out : ((l & 1) ? ws1 : ws0);

        if (t < JT) {      // wave 0 exactly
            float s = partial[t] + partial[t + 64] + partial[t + 128] + partial[t + 192];
            const int idx = b * D + j0 + t;
            const size_t lidx = (size_t)l * B * D + idx;
            s += ball[lidx];
            if (mall[lidx]) s = fmaxf(s, 0.f);
            if (last) {
                hout[idx] = s;
            } else {
                // Publish through to the LLC (coherence point); no L2 dirty state.
                __hip_atomic_store(&hout[idx], s, __ATOMIC_RELAXED,
                                   __HIP_MEMORY_SCOPE_AGENT);
                // Wave-level order: h-stores reach LLC before the signal below.
                asm volatile("s_waitcnt vmcnt(0)" ::: "memory");
                if (t == 0)
                    __hip_atomic_fetch_add(&cnt[l * B + b], 1, __ATOMIC_RELAXED,
                                           __HIP_MEMORY_SCOPE_AGENT);
            }
        }
        if (last) break;

        // Issue next layer's W prefetch BEFORE spinning: ~8KB/block of HBM
        // traffic stays in flight through the barrier.
        const float* wn = Wall + ((size_t)(l + 1) * B + b) * D * D + j;
#pragma unroll
        for (int k = 0; k < PF; ++k) pf[k] = wn[(size_t)(i_beg + k) * D];
        w = wn;

        // Per-batch barrier: relaxed LLC polls only (no cache invalidates).
        if (t == 0) {
            while (__hip_atomic_load(&cnt[l * B + b], __ATOMIC_RELAXED,
                                     __HIP_MEMORY_SCOPE_AGENT) < NBB)
                __builtin_amdgcn_s_sleep(1);
        }
        __syncthreads();

        // Re-stage h from the LLC (relaxed agent loads bypass stale L1/L2).
        for (int i = t; i < D; i += BLOCK)
            hs[i] = __hip_atomic_load(&hout[b * D + i], __ATOMIC_RELAXED,
                                      __HIP_MEMORY_SCOPE_AGENT);
        __syncthreads();
    }
}

extern "C" void kernel_launch(void* const* d_in, const int* in_sizes, int n_in,
                              void* d_out, int out_size, void* d_ws, size_t ws_size,
                              hipStream_t stream) {
    const float* x       = (const float*)d_in[0];  // [B, D]
    const float* weights = (const float*)d_in[1];  // [L, B, D, D]
    const float* biases  = (const float*)d_in[2];  // [L, B, D]
    const int*   masks   = (const int*)  d_in[3];  // [L, B, D]
    float* out = (float*)d_out;                    // [B, D]

    float* ws0 = (float*)d_ws;
    float* ws1 = ws0 + B * D;
    int*   cnt = (int*)(ws1 + B * D);              // [L, B]

    // Counters must be zero at kernel start every call (replays don't
    // re-poison d_ws). hipMemsetAsync is graph-capture-safe.
    hipMemsetAsync(cnt, 0, L * B * sizeof(int), stream);

    dim3 grid(D / JT, B);
    dim3 block(BLOCK);
    fused_kernel<<<grid, block, 0, stream>>>(x, weights, biases, masks,
                                             out, ws0, ws1, cnt);
}

// Round 7
// 402.912 us; speedup vs baseline: 1.2597x; 1.2597x over previous
//
#include <hip/hip_runtime.h>
#include <hip/hip_bf16.h>

// Problem constants (from reference): L layers, B batch, D width.
constexpr int L = 8;
constexpr int B = 32;
constexpr int D = 1280;

constexpr int JT    = 64;            // output columns per block
constexpr int BLOCK = 256;
constexpr int NJG   = JT / 4;        // 16 column-groups of float4
constexpr int ISPL  = BLOCK / NJG;   // 16-way i-split
constexpr int ICH   = D / ISPL;      // 80 i-rows per thread

// One layer: h_out[b,j] = maskrelu( sum_i h_in[b,i]*W[b,i,j] + bias[b,j] )
// grid = (D/JT, B) = (20,32) = 640 blocks (all co-resident; R4 measured 28.8%
// occupancy at this geometry). W streamed as float4 along j: 1KB per
// wave-instruction, fully contiguous 256B segments, 4x fewer load instrs
// and 4x more bytes per vmcnt slot than the scalar-dword R1 version.
__global__ __launch_bounds__(BLOCK) void layer_kernel(
    const float* __restrict__ h_in,   // [B, D]
    const float* __restrict__ W,      // [B, D, D]
    const float* __restrict__ bias,   // [B, D]
    const int*   __restrict__ mask,   // [B, D]
    float*       __restrict__ h_out)  // [B, D]
{
    const int b  = blockIdx.y;
    const int j0 = blockIdx.x * JT;
    const int t  = threadIdx.x;
    const int jg = t & (NJG - 1);   // 0..15 column-group (j = j0 + jg*4 .. +3)
    const int ig = t >> 4;          // 0..15 i-split index
    const int i_beg = ig * ICH;

    __shared__ float  hs[D];
    __shared__ float4 p4[ISPL][NJG];

    // Stage h[b,:] into LDS (float4, coalesced; broadcast reads later).
    {
        const float4* src = (const float4*)(h_in + b * D);
        float4* dst = (float4*)hs;
        for (int k = t; k < D / 4; k += BLOCK) dst[k] = src[k];
    }
    __syncthreads();

    // Stream this thread's 80 W rows as float4; accumulate 4 columns.
    const float* wbase = W + (size_t)b * D * D + j0 + jg * 4;
    float4 acc = {0.f, 0.f, 0.f, 0.f};
#pragma unroll 16
    for (int i = i_beg; i < i_beg + ICH; ++i) {
        const float4 wv = *(const float4*)(wbase + (size_t)i * D);
        const float  h  = hs[i];
        acc.x = fmaf(h, wv.x, acc.x);
        acc.y = fmaf(h, wv.y, acc.y);
        acc.z = fmaf(h, wv.z, acc.z);
        acc.w = fmaf(h, wv.w, acc.w);
    }

    p4[ig][jg] = acc;
    __syncthreads();

    // 64 threads finalize one column each; LDS reads are conflict-free
    // (word index = g*64 + t, consecutive across t for fixed g).
    if (t < JT) {
        float s = 0.f;
        const float* pp = (const float*)p4;
#pragma unroll
        for (int g = 0; g < ISPL; ++g) s += pp[g * JT + t];
        const int idx = b * D + j0 + t;
        s += bias[idx];
        if (mask[idx]) s = fmaxf(s, 0.f);
        h_out[idx] = s;
    }
}

extern "C" void kernel_launch(void* const* d_in, const int* in_sizes, int n_in,
                              void* d_out, int out_size, void* d_ws, size_t ws_size,
                              hipStream_t stream) {
    const float* x       = (const float*)d_in[0];  // [B, D]
    const float* weights = (const float*)d_in[1];  // [L, B, D, D]
    const float* biases  = (const float*)d_in[2];  // [L, B, D]
    const int*   masks   = (const int*)  d_in[3];  // [L, B, D]
    float* out = (float*)d_out;                    // [B, D]

    // Ping-pong h through workspace; final layer writes d_out.
    float* ws0 = (float*)d_ws;
    float* ws1 = ws0 + B * D;

    dim3 grid(D / JT, B);
    dim3 block(BLOCK);

    const float* hin = x;
    for (int l = 0; l < L; ++l) {
        float* hout = (l == L - 1) ? out : ((l & 1) ? ws1 : ws0);
        layer_kernel<<<grid, block, 0, stream>>>(
            hin,
            weights + (size_t)l * B * D * D,
            biases  + (size_t)l * B * D,
            masks   + (size_t)l * B * D,
            hout);
        hin = hout;
    }
}

// Round 8
// 316.117 us; speedup vs baseline: 1.6056x; 1.2746x over previous
//
#include <hip/hip_runtime.h>
#include <hip/hip_bf16.h>

// Problem constants (from reference): L layers, B batch, D width.
constexpr int L = 8;
constexpr int B = 32;
constexpr int D = 1280;

// ---------------- sequential-stream split-K path ----------------
constexpr int NIC   = 16;           // i-chunks per batch -> grid 32*16=512 = 2/CU exactly
constexpr int ROWS  = D / NIC;      // 80 rows per block
constexpr int BLOCK = 256;          // 4 waves
constexpr int WAVES = 4;
constexpr int RPW   = ROWS / WAVES; // 20 rows per wave
constexpr int NQ    = D / 256;      // 5 float4 accumulators per thread

// Block (b,ic): reads W[b, i0..i0+79, :] -- a CONTIGUOUS 400KB slab.
// Per wave-instruction: 64 lanes x float4 = 1KB contiguous; rows sequential.
// Produces 1280 partial sums, atomicAdd'ed into acc[l][b][:].
// maskrelu of the PREVIOUS layer is applied while staging h (elementwise).
__global__ __launch_bounds__(BLOCK) void layer_seq_kernel(
    const float* __restrict__ x,        // [B,D] (layer-0 input)
    const float* __restrict__ Wl,       // [B,D,D] this layer
    const float* __restrict__ bias_l,   // [B,D] this layer
    const float* __restrict__ accprev,  // acc[l-1] or nullptr if l==0
    const int*   __restrict__ maskprev, // masks[l-1] or nullptr
    float*       __restrict__ accout)   // acc[l] (pre-zeroed)
{
    const int b    = blockIdx.y;
    const int ic   = blockIdx.x;
    const int i0   = ic * ROWS;
    const int t    = threadIdx.x;
    const int w    = t >> 6;
    const int lane = t & 63;

    __shared__ float hs[ROWS];
    __shared__ float p[WAVES][D];   // 20KB cross-wave partials

    // Stage h chunk (80 floats) with fused maskrelu of previous layer.
    if (t < ROWS / 4) {
        const int ii = 4 * t;
        float4 v;
        if (accprev == nullptr) {
            v = *(const float4*)(x + (size_t)b * D + i0 + ii);
        } else {
            v = *(const float4*)(accprev + (size_t)b * D + i0 + ii);
            const int4 m = *(const int4*)(maskprev + (size_t)b * D + i0 + ii);
            if (m.x) v.x = fmaxf(v.x, 0.f);
            if (m.y) v.y = fmaxf(v.y, 0.f);
            if (m.z) v.z = fmaxf(v.z, 0.f);
            if (m.w) v.w = fmaxf(v.w, 0.f);
        }
        *(float4*)(hs + ii) = v;
    }
    __syncthreads();

    float4 acc[NQ];
#pragma unroll
    for (int q = 0; q < NQ; ++q) acc[q] = make_float4(0.f, 0.f, 0.f, 0.f);

    // Wave w walks rows [i0+20w, i0+20w+20) fully sequentially.
    const float4* wrow = (const float4*)(Wl + ((size_t)b * D + i0 + w * RPW) * D);
#pragma unroll 4
    for (int r = 0; r < RPW; ++r) {
        const float hv = hs[w * RPW + r];          // LDS broadcast
        const float4* row = wrow + (size_t)r * (D / 4);
#pragma unroll
        for (int q = 0; q < NQ; ++q) {
            const float4 wv = row[q * 64 + lane];  // 1KB contiguous per instr
            acc[q].x = fmaf(hv, wv.x, acc[q].x);
            acc[q].y = fmaf(hv, wv.y, acc[q].y);
            acc[q].z = fmaf(hv, wv.z, acc[q].z);
            acc[q].w = fmaf(hv, wv.w, acc[q].w);
        }
    }

    // Cross-wave reduce in LDS, then one atomicAdd per (thread, k).
#pragma unroll
    for (int q = 0; q < NQ; ++q)
        *(float4*)(&p[w][q * 256 + 4 * lane]) = acc[q];
    __syncthreads();

    const float* bb = bias_l + (size_t)b * D;
#pragma unroll
    for (int k = 0; k < NQ; ++k) {
        const int j = t + 256 * k;                 // conflict-free LDS banks
        float s = p[0][j] + p[1][j] + p[2][j] + p[3][j];
        if (ic == 0) s += bb[j];                   // bias added exactly once
        atomicAdd(accout + (size_t)b * D + j, s);
    }
}

// Final epilogue: out = maskrelu_{L-1}(acc[L-1]).
__global__ __launch_bounds__(256) void finish_kernel(
    const float* __restrict__ acc7, const int* __restrict__ mask7,
    float* __restrict__ out)
{
    const int idx = blockIdx.x * 256 + threadIdx.x;
    if (idx < B * D) {
        float v = acc7[idx];
        if (mask7[idx]) v = fmaxf(v, 0.f);
        out[idx] = v;
    }
}

// ---------------- fallback: proven R1 j-tile path ----------------
constexpr int JT = 64;
constexpr int ISPLIT = 4;
constexpr int FBLOCK = JT * ISPLIT;   // 256
constexpr int ICHUNK = D / ISPLIT;    // 320

__global__ __launch_bounds__(FBLOCK) void layer_kernel(
    const float* __restrict__ h_in, const float* __restrict__ W,
    const float* __restrict__ bias, const int* __restrict__ mask,
    float* __restrict__ h_out)
{
    const int b  = blockIdx.y;
    const int j0 = blockIdx.x * JT;
    const int t  = threadIdx.x;
    const int jj = t & (JT - 1);
    const int iq = t >> 6;
    const int j  = j0 + jj;

    __shared__ float hs[D];
    __shared__ float partial[FBLOCK];

    for (int i = t; i < D; i += FBLOCK) hs[i] = h_in[b * D + i];
    __syncthreads();

    const float* w = W + (size_t)b * D * D + j;
    const int i_beg = iq * ICHUNK;
    float acc = 0.f;
#pragma unroll 8
    for (int i = i_beg; i < i_beg + ICHUNK; ++i)
        acc = fmaf(hs[i], w[(size_t)i * D], acc);

    partial[t] = acc;
    __syncthreads();

    if (t < JT) {
        float s = partial[t] + partial[t + 64] + partial[t + 128] + partial[t + 192];
        const int idx = b * D + j0 + t;
        s += bias[idx];
        if (mask[idx]) s = fmaxf(s, 0.f);
        h_out[idx] = s;
    }
}

extern "C" void kernel_launch(void* const* d_in, const int* in_sizes, int n_in,
                              void* d_out, int out_size, void* d_ws, size_t ws_size,
                              hipStream_t stream) {
    const float* x       = (const float*)d_in[0];  // [B, D]
    const float* weights = (const float*)d_in[1];  // [L, B, D, D]
    const float* biases  = (const float*)d_in[2];  // [L, B, D]
    const int*   masks   = (const int*)  d_in[3];  // [L, B, D]
    float* out = (float*)d_out;                    // [B, D]

    const size_t need = (size_t)L * B * D * sizeof(float);  // 1.31 MB

    if (ws_size >= need) {
        float* acc = (float*)d_ws;                 // [L, B, D] accumulators
        hipMemsetAsync(acc, 0, need, stream);      // graph-capture-safe

        dim3 grid(NIC, B);
        for (int l = 0; l < L; ++l) {
            layer_seq_kernel<<<grid, BLOCK, 0, stream>>>(
                x,
                weights + (size_t)l * B * D * D,
                biases  + (size_t)l * B * D,
                l ? acc + (size_t)(l - 1) * B * D : nullptr,
                l ? masks + (size_t)(l - 1) * B * D : nullptr,
                acc + (size_t)l * B * D);
        }
        finish_kernel<<<(B * D + 255) / 256, 256, 0, stream>>>(
            acc + (size_t)(L - 1) * B * D, masks + (size_t)(L - 1) * B * D, out);
    } else {
        // Fallback: proven 8-dispatch j-tile path (needs 320KB ws).
        float* ws0 = (float*)d_ws;
        float* ws1 = ws0 + B * D;
        dim3 grid(D / JT, B);
        const float* hin = x;
        for (int l = 0; l < L; ++l) {
            float* hout = (l == L - 1) ? out : ((l & 1) ? ws1 : ws0);
            layer_kernel<<<grid, FBLOCK, 0, stream>>>(
                hin,
                weights + (size_t)l * B * D * D,
                biases  + (size_t)l * B * D,
                masks   + (size_t)l * B * D,
                hout);
            hin = hout;
        }
    }
}